// Round 3
// baseline (120.827 us; speedup 1.0000x reference)
//
#include <hip/hip_runtime.h>
#include <hip/hip_bf16.h>
#include <math.h>

// Problem: B=4, L=2048 (M = 8192 rows), D_MODEL = 768, N_STATE = 16.
// y[row,d] = x[row,d] * softplus((x@W1+b1)[row,d]) * dot(x@W2+b2, x@W3+b3)[row]
// (dA*h0 term is identically zero; A unused.)
// Ledger: ~62 us harness fills per iter (fixed). R10: direct-from-global GEMM
// loses 2x -> LDS+barrier k-loop. R11: fold s into the gemm. R12: fuse x->bf16
// into A-staging (killed the 38 MB stream) but exposed load latency per step
// (issue-then-drain same phase) -> +11 us gemm. R13: 2-deep pipeline — all
// loads issued one full phase before consumption; syncthreads' vmcnt(0) drain
// only ever hits ~1-phase-old loads. Wl LDS dropped: W frags direct
// global->reg (48 KB w23t is L2-hot; swizzle cancels). R14: resubmit of R13 —
// container-level infra failure, no counters; kernel re-audited (barriers
// uniform, buffer lifetimes race-free, addresses aligned/in-bounds).

#define M_ROWS 8192
#define DM 768
#define NS 16
#define NT 12   // k-steps: 768 / 64

typedef short bf16x8 __attribute__((ext_vector_type(8)));
typedef unsigned short u16x8 __attribute__((ext_vector_type(8)));
typedef float f32x4 __attribute__((ext_vector_type(4)));

__device__ __forceinline__ unsigned short f2bf(float f) {
    union { float f; unsigned u; } v; v.f = f;
    unsigned r = v.u + 0x7FFF + ((v.u >> 16) & 1);   // RNE
    return (unsigned short)(r >> 16);
}
// compiler lowers scalar casts to packed v_cvt_pk_bf16_f32 (RNE) on gfx950
__device__ __forceinline__ unsigned short cvtbf(float f) {
    __hip_bfloat16 h = __float2bfloat16(f);
    return *reinterpret_cast<unsigned short*>(&h);
}
__device__ __forceinline__ void async16(const void* g, void* l) {
    __builtin_amdgcn_global_load_lds(
        (const __attribute__((address_space(1))) void*)g,
        (__attribute__((address_space(3))) void*)l,
        16, 0, 0);
}
// branchless stable softplus: max(v,0) + log(1+exp(-|v|)); HW exp/log.
__device__ __forceinline__ float softplus_fast(float v) {
    return fmaxf(v, 0.f) + __logf(1.f + __expf(-fabsf(v)));
}

// ---- kernel 1: W-prep only (608 blocks) ---------------------------------
// bid [0,32):   w23t build (bf16 n-major, pair-interleaved W2/W3 cols).
// bid [32,608): W1 [k][n] fp32 -> w1t [n][k] bf16 (32x32 LDS tiles).
__global__ __launch_bounds__(256) void prep_kernel(
    const float* __restrict__ W1,
    const float* __restrict__ W2,
    const float* __restrict__ W3,
    unsigned short* __restrict__ w1t,
    unsigned short* __restrict__ w23t)
{
    __shared__ float tile[32][33];
    const int bid = blockIdx.x;
    const int tid = threadIdx.x;
    if (bid < 32) {
        const int n = bid, i = n >> 1;
        const float* src = (n & 1) ? W3 : W2;
        #pragma unroll
        for (int e = 0; e < 3; ++e) {
            int k = e * 256 + tid;
            w23t[n * DM + k] = f2bf(src[k * NS + i]);
        }
    } else {
        const int b2i = bid - 32;                // 0..575
        const int n0 = (b2i % 24) * 32, k0 = (b2i / 24) * 32;
        const int tx = tid & 31, ty = tid >> 5;  // 32 x 8
        #pragma unroll
        for (int i = 0; i < 4; ++i) {
            int k = ty + i * 8;
            tile[k][tx] = W1[(k0 + k) * DM + n0 + tx];
        }
        __syncthreads();
        #pragma unroll
        for (int i = 0; i < 4; ++i) {
            int n = ty + i * 8;
            w1t[(n0 + n) * DM + k0 + tx] = f2bf(tile[tx][n]);
        }
    }
}

// ---- kernel 2: pipelined fused cvt + GEMM + s + softplus epilogue -------
// 2-deep pipeline, double-buffered LDS (Al/Bl x2 = 48 KB + 1 KB spart ->
// 3 blocks/CU). Per iter: COMPUTE(buf[t&1]) ; cvt+ds_write A(t+1)->buf[~];
// __syncthreads (drains 1-phase-old async16 B(t+1) + the ds_writes);
// issue A(t+2)/W(t+2) reg loads + async16 B(t+2). Fragment algebra, shfl
// s-reduction and epilogue are byte-identical to the verified R11/R12 code.
__global__ __launch_bounds__(256) void gemm_fused_kernel(
    const float* __restrict__ x,              // [8192][768] fp32
    const unsigned short* __restrict__ w1t,   // [768][768] bf16, n-major
    const unsigned short* __restrict__ w23t,  // [32][768] bf16, pair-interleaved
    const float* __restrict__ b1,
    const float* __restrict__ b2, const float* __restrict__ b3,
    float* __restrict__ y)
{
    __shared__ unsigned short Al[2][128 * 64];   // 32 KB
    __shared__ unsigned short Bl[2][64 * 64];    // 16 KB
    __shared__ float spart[2][128];              //  1 KB
    const int b = blockIdx.x;
    const int c = b & 7, j = b >> 3;          // j in [0,96)
    const int m0 = (c * 8 + j / 12) * 128;
    const int n0 = (j % 12) * 64;
    const int tid  = threadIdx.x;
    const int lane = tid & 63;
    const int wave = tid >> 6;
    const int wm = wave >> 1, wn = wave & 1;
    const int l15 = lane & 15, quad = lane >> 4;

    f32x4 acc[4][2];
    f32x4 accP[4];
    #pragma unroll
    for (int i = 0; i < 4; ++i) {
        accP[i] = (f32x4){0.f, 0.f, 0.f, 0.f};
        #pragma unroll
        for (int jj = 0; jj < 2; ++jj)
            acc[i][jj] = (f32x4){0.f, 0.f, 0.f, 0.f};
    }

    float4 va[8];        // in-flight A rows (fp32), one k-step ahead
    bf16x8 vw[2][2];     // W23 fragments, [parity][kk], one k-step ahead

    // A reg-load for k-step T (8 dwordx4; swizzled layout matched to store)
#define LOAD_A(T) do {                                                     \
        const int k0_ = (T) * 64;                                          \
        _Pragma("unroll")                                                  \
        for (int i_ = 0; i_ < 4; ++i_) {                                   \
            int ch_ = tid + i_ * 256;                                      \
            int r_ = ch_ >> 3, jg_ = (ch_ & 7) ^ (r_ & 7);                 \
            const float4* s_ = (const float4*)(x + (m0 + r_) * DM + k0_ + jg_ * 8); \
            va[2 * i_]     = s_[0];                                        \
            va[2 * i_ + 1] = s_[1];                                        \
        }                                                                  \
    } while (0)

    // W23 fragment reg-load for k-step T (direct global; swizzle cancels)
#define LOAD_W(P, T) do {                                                  \
        const int k0_ = (T) * 64;                                          \
        const int rw_ = wn * 16 + l15;                                     \
        _Pragma("unroll")                                                  \
        for (int kk_ = 0; kk_ < 2; ++kk_)                                  \
            vw[P][kk_] = *(const bf16x8*)(w23t + rw_ * DM + k0_ + (kk_ * 4 + quad) * 8); \
    } while (0)

    // B LDS staging for k-step T into buffer P (2 async16/thread)
#define STAGE_B(P, T) do {                                                 \
        const int k0_ = (T) * 64;                                          \
        _Pragma("unroll")                                                  \
        for (int i_ = 0; i_ < 2; ++i_) {                                   \
            int ch_ = tid + i_ * 256;                                      \
            int r_ = ch_ >> 3, jg_ = (ch_ & 7) ^ (r_ & 7);                 \
            async16(w1t + (n0 + r_) * DM + k0_ + jg_ * 8, &Bl[P][ch_ * 8]); \
        }                                                                  \
    } while (0)

    // cvt va -> bf16, ds_write into Al buffer P (4 b128 writes/thread)
#define CVT_WRITE_A(P) do {                                                \
        _Pragma("unroll")                                                  \
        for (int i_ = 0; i_ < 4; ++i_) {                                   \
            int ch_ = tid + i_ * 256;                                      \
            float4 a_ = va[2 * i_], b_ = va[2 * i_ + 1];                   \
            u16x8 o_;                                                      \
            o_[0] = cvtbf(a_.x); o_[1] = cvtbf(a_.y);                      \
            o_[2] = cvtbf(a_.z); o_[3] = cvtbf(a_.w);                      \
            o_[4] = cvtbf(b_.x); o_[5] = cvtbf(b_.y);                      \
            o_[6] = cvtbf(b_.z); o_[7] = cvtbf(b_.w);                      \
            *(u16x8*)(&Al[P][ch_ * 8]) = o_;                               \
        }                                                                  \
    } while (0)

    // ---- prologue: stage t=0, prefetch t=1 ----
    LOAD_A(0);
    LOAD_W(0, 0);
    STAGE_B(0, 0);
    CVT_WRITE_A(0);          // compiler inserts the vmcnt wait for va here
    LOAD_A(1);
    LOAD_W(1, 1);
    __syncthreads();         // drains B(0) async16 + A(0) ds_writes
    STAGE_B(1, 1);

    // ---- main loop: 2-deep pipeline ----
    #pragma unroll
    for (int t = 0; t < NT; ++t) {
        const int cur = t & 1;
        // compute on buf[cur]; W frags from regs (vw[cur])
        #pragma unroll
        for (int kk = 0; kk < 2; ++kk) {
            bf16x8 bfr[2];
            #pragma unroll
            for (int jj = 0; jj < 2; ++jj) {
                int rb = wn * 32 + jj * 16 + l15;
                int jb = (kk * 4 + quad) ^ (rb & 7);
                bfr[jj] = *(const bf16x8*)(&Bl[cur][rb * 64 + jb * 8]);
            }
            bf16x8 wfr = vw[cur][kk];
            #pragma unroll
            for (int i = 0; i < 4; ++i) {
                int rr = wm * 64 + i * 16 + l15;
                int ja = (kk * 4 + quad) ^ (rr & 7);
                bf16x8 af = *(const bf16x8*)(&Al[cur][rr * 64 + ja * 8]);
                #pragma unroll
                for (int jj = 0; jj < 2; ++jj)
                    acc[i][jj] = __builtin_amdgcn_mfma_f32_16x16x32_bf16(
                        af, bfr[jj], acc[i][jj], 0, 0, 0);
                accP[i] = __builtin_amdgcn_mfma_f32_16x16x32_bf16(
                    af, wfr, accP[i], 0, 0, 0);
            }
        }
        if (t + 1 < NT) {
            CVT_WRITE_A(cur ^ 1);            // A(t+1): regs arrived during compute
            __syncthreads();                 // drains 1-phase-old B(t+1) + ds_writes
            if (t + 2 < NT) {
                LOAD_A(t + 2);               // issue next-next A (hidden under compute t+1)
                LOAD_W(cur, t + 2);          // parity (t+2)&1 == cur
                STAGE_B(cur, t + 2);         // into buf just freed by compute(t)
            }
        }
    }

    // ---- s partials: this wave owns pairs p = wn*8 + (l15>>1) ----
    {
        const int p = wn * 8 + (l15 >> 1);
        const float bB = b2[p], bC = b3[p];
        #pragma unroll
        for (int i = 0; i < 4; ++i) {
            float sacc[4];
            #pragma unroll
            for (int r = 0; r < 4; ++r) {
                float v = accP[i][r];
                float pv = __shfl_xor(v, 1, 64);
                sacc[r] = (l15 & 1) ? (pv + bB) * (v + bC)
                                    : (v + bB) * (pv + bC);
                sacc[r] += __shfl_xor(sacc[r], 1, 64);
                sacc[r] += __shfl_xor(sacc[r], 2, 64);
                sacc[r] += __shfl_xor(sacc[r], 4, 64);
                sacc[r] += __shfl_xor(sacc[r], 8, 64);
            }
            if (l15 == 0) {
                #pragma unroll
                for (int r = 0; r < 4; ++r)
                    spart[wn][wm * 64 + i * 16 + quad * 4 + r] = 0.5f * sacc[r];
            }
        }
    }
    __syncthreads();

    // ---- epilogue: C/D layout col = lane&15, row = quad*4 + reg ----
    // xv read from x fp32 (L2-hot: this block just streamed its row-panel)
    #pragma unroll
    for (int i = 0; i < 4; ++i) {
        const int rl = wm * 64 + i * 16 + quad * 4;   // local row base
        const int rowbase = m0 + rl;
        float sv4[4];
        #pragma unroll
        for (int r = 0; r < 4; ++r)
            sv4[r] = spart[0][rl + r] + spart[1][rl + r];
        #pragma unroll
        for (int jj = 0; jj < 2; ++jj) {
            int gcol = n0 + wn * 32 + jj * 16 + l15;
            float bias = b1[gcol];
            #pragma unroll
            for (int r = 0; r < 4; ++r) {
                int grow = rowbase + r;
                float v = acc[i][jj][r] + bias;
                float sp = softplus_fast(v);
                float xv = x[grow * DM + gcol];
                y[grow * DM + gcol] = xv * sp * sv4[r];
            }
        }
    }
#undef LOAD_A
#undef LOAD_W
#undef STAGE_B
#undef CVT_WRITE_A
}

extern "C" void kernel_launch(void* const* d_in, const int* in_sizes, int n_in,
                              void* d_out, int out_size, void* d_ws, size_t ws_size,
                              hipStream_t stream) {
    const float* x  = (const float*)d_in[0];
    const float* W1 = (const float*)d_in[1];
    const float* b1 = (const float*)d_in[2];
    const float* W2 = (const float*)d_in[3];
    const float* b2 = (const float*)d_in[4];
    const float* W3 = (const float*)d_in[5];
    const float* b3 = (const float*)d_in[6];
    // d_in[7] = A : unused (multiplied by h0 == 0 in the reference)
    float* y = (float*)d_out;

    unsigned short* w1t  = (unsigned short*)d_ws;                     // 1,179,648 B
    unsigned short* w23t = (unsigned short*)((char*)d_ws + 1179648);  //    49,152 B

    prep_kernel<<<608, 256, 0, stream>>>(W1, W2, W3, w1t, w23t);
    gemm_fused_kernel<<<768, 256, 0, stream>>>(x, w1t, w23t, b1, b2, b3, y);
}

// Round 4
// 120.312 us; speedup vs baseline: 1.0043x; 1.0043x over previous
//
#include <hip/hip_runtime.h>
#include <hip/hip_bf16.h>
#include <math.h>

// Problem: B=4, L=2048 (M = 8192 rows), D_MODEL = 768, N_STATE = 16.
// y[row,d] = x[row,d] * softplus((x@W1+b1)[row,d]) * dot(x@W2+b2, x@W3+b3)[row]
// (dA*h0 term is identically zero; A unused.)
// Ledger: ~62 us harness fills per iter (fixed). R10: direct-from-global GEMM
// loses 2x -> LDS+barrier k-loop. R11: fold s into gemm. R12/R13: fuse x->bf16
// into A-staging; pipeline attempts under __syncthreads all land ~40-44 us
// because syncthreads' vmcnt(0) force-drains EVERY outstanding load each iter
// (m233: 2-phase ~72% overhead). R15 (this round): counted-vmcnt + raw
// s_barrier (T4). One manual sync/iter: s_waitcnt vmcnt(8) lgkmcnt(0) +
// s_barrier; the 8 A-loads of step t+2 stay in flight ACROSS the barrier.
// A issued 2 phases ahead (va dbuf), W/B 1 phase ahead. sched_barrier(0)
// pins issue order at section boundaries so the hand counts stay valid.

#define M_ROWS 8192
#define DM 768
#define NS 16
#define NT 12   // k-steps: 768 / 64

typedef short bf16x8 __attribute__((ext_vector_type(8)));
typedef unsigned short u16x8 __attribute__((ext_vector_type(8)));
typedef float f32x4 __attribute__((ext_vector_type(4)));

__device__ __forceinline__ unsigned short f2bf(float f) {
    union { float f; unsigned u; } v; v.f = f;
    unsigned r = v.u + 0x7FFF + ((v.u >> 16) & 1);   // RNE
    return (unsigned short)(r >> 16);
}
// compiler lowers scalar casts to packed v_cvt_pk_bf16_f32 (RNE) on gfx950
__device__ __forceinline__ unsigned short cvtbf(float f) {
    __hip_bfloat16 h = __float2bfloat16(f);
    return *reinterpret_cast<unsigned short*>(&h);
}
__device__ __forceinline__ void async16(const void* g, void* l) {
    __builtin_amdgcn_global_load_lds(
        (const __attribute__((address_space(1))) void*)g,
        (__attribute__((address_space(3))) void*)l,
        16, 0, 0);
}
// branchless stable softplus: max(v,0) + log(1+exp(-|v|)); HW exp/log.
__device__ __forceinline__ float softplus_fast(float v) {
    return fmaxf(v, 0.f) + __logf(1.f + __expf(-fabsf(v)));
}

#define FENCE() __builtin_amdgcn_sched_barrier(0)

// ---- kernel 1: W-prep only (608 blocks) ---------------------------------
__global__ __launch_bounds__(256) void prep_kernel(
    const float* __restrict__ W1,
    const float* __restrict__ W2,
    const float* __restrict__ W3,
    unsigned short* __restrict__ w1t,
    unsigned short* __restrict__ w23t)
{
    __shared__ float tile[32][33];
    const int bid = blockIdx.x;
    const int tid = threadIdx.x;
    if (bid < 32) {
        const int n = bid, i = n >> 1;
        const float* src = (n & 1) ? W3 : W2;
        #pragma unroll
        for (int e = 0; e < 3; ++e) {
            int k = e * 256 + tid;
            w23t[n * DM + k] = f2bf(src[k * NS + i]);
        }
    } else {
        const int b2i = bid - 32;                // 0..575
        const int n0 = (b2i % 24) * 32, k0 = (b2i / 24) * 32;
        const int tx = tid & 31, ty = tid >> 5;  // 32 x 8
        #pragma unroll
        for (int i = 0; i < 4; ++i) {
            int k = ty + i * 8;
            tile[k][tx] = W1[(k0 + k) * DM + n0 + tx];
        }
        __syncthreads();
        #pragma unroll
        for (int i = 0; i < 4; ++i) {
            int n = ty + i * 8;
            w1t[(n0 + n) * DM + k0 + tx] = f2bf(tile[tx][n]);
        }
    }
}

// ---- kernel 2: counted-vmcnt pipelined GEMM + s + softplus epilogue -----
// Steady-state iter t (cur=t&1, nxt=cur^1):
//  entry outstanding (oldest->newest): A(t+1):8, W(t+1):2, B(t+1->Bl[nxt]):2
//  S1: issue A(t+2)->va[cur]                         (20 outstanding)
//  S2: compute(t) on Al[cur]/Bl[cur]/vw[cur]
//  S3: cvt va[nxt] -> ds_write Al[nxt]   (compiler waits vmcnt<=12 for va)
//  S4: s_waitcnt vmcnt(8) lgkmcnt(0); s_barrier      (A(t+2) stays in flight)
//  S5: issue W(t+2)->vw[cur], B(t+2)->Bl[cur]        (12 outstanding)
// Race sweep: writes between barrier(t-1)..barrier(t) touch only Al[nxt]/
// Bl[nxt]; reads touch only Al[cur]/Bl[cur]. B(t+2)->Bl[cur] issues after
// barrier(t), when all waves' Bl[cur] reads are consumed.
__global__ __launch_bounds__(256, 3) void gemm_fused_kernel(
    const float* __restrict__ x,              // [8192][768] fp32
    const unsigned short* __restrict__ w1t,   // [768][768] bf16, n-major
    const unsigned short* __restrict__ w23t,  // [32][768] bf16, pair-interleaved
    const float* __restrict__ b1,
    const float* __restrict__ b2, const float* __restrict__ b3,
    float* __restrict__ y)
{
    __shared__ unsigned short Al[2][128 * 64];   // 32 KB
    __shared__ unsigned short Bl[2][64 * 64];    // 16 KB
    __shared__ float spart[2][128];              //  1 KB
    const int b = blockIdx.x;
    const int c = b & 7, j = b >> 3;          // j in [0,96)
    const int m0 = (c * 8 + j / 12) * 128;
    const int n0 = (j % 12) * 64;
    const int tid  = threadIdx.x;
    const int lane = tid & 63;
    const int wave = tid >> 6;
    const int wm = wave >> 1, wn = wave & 1;
    const int l15 = lane & 15, quad = lane >> 4;

    f32x4 acc[4][2];
    f32x4 accP[4];
    #pragma unroll
    for (int i = 0; i < 4; ++i) {
        accP[i] = (f32x4){0.f, 0.f, 0.f, 0.f};
        #pragma unroll
        for (int jj = 0; jj < 2; ++jj)
            acc[i][jj] = (f32x4){0.f, 0.f, 0.f, 0.f};
    }

    float4 va[2][8];     // A fp32 in flight, 2 k-steps deep
    bf16x8 vw[2][2];     // W23 fragments, 1 k-step deep

#define LOAD_A(P, T) do {                                                  \
        const int k0_ = (T) * 64;                                          \
        _Pragma("unroll")                                                  \
        for (int i_ = 0; i_ < 4; ++i_) {                                   \
            int ch_ = tid + i_ * 256;                                      \
            int r_ = ch_ >> 3, jg_ = (ch_ & 7) ^ (r_ & 7);                 \
            const float4* s_ = (const float4*)(x + (m0 + r_) * DM + k0_ + jg_ * 8); \
            va[P][2 * i_]     = s_[0];                                     \
            va[P][2 * i_ + 1] = s_[1];                                     \
        }                                                                  \
    } while (0)

#define LOAD_W(P, T) do {                                                  \
        const int k0_ = (T) * 64;                                          \
        const int rw_ = wn * 16 + l15;                                     \
        _Pragma("unroll")                                                  \
        for (int kk_ = 0; kk_ < 2; ++kk_)                                  \
            vw[P][kk_] = *(const bf16x8*)(w23t + rw_ * DM + k0_ + (kk_ * 4 + quad) * 8); \
    } while (0)

#define STAGE_B(P, T) do {                                                 \
        const int k0_ = (T) * 64;                                          \
        _Pragma("unroll")                                                  \
        for (int i_ = 0; i_ < 2; ++i_) {                                   \
            int ch_ = tid + i_ * 256;                                      \
            int r_ = ch_ >> 3, jg_ = (ch_ & 7) ^ (r_ & 7);                 \
            async16(w1t + (n0 + r_) * DM + k0_ + jg_ * 8, &Bl[P][ch_ * 8]); \
        }                                                                  \
    } while (0)

#define CVT_WRITE_A(P) do {                                                \
        _Pragma("unroll")                                                  \
        for (int i_ = 0; i_ < 4; ++i_) {                                   \
            int ch_ = tid + i_ * 256;                                      \
            float4 a_ = va[P][2 * i_], b_ = va[P][2 * i_ + 1];             \
            u16x8 o_;                                                      \
            o_[0] = cvtbf(a_.x); o_[1] = cvtbf(a_.y);                      \
            o_[2] = cvtbf(a_.z); o_[3] = cvtbf(a_.w);                      \
            o_[4] = cvtbf(b_.x); o_[5] = cvtbf(b_.y);                      \
            o_[6] = cvtbf(b_.z); o_[7] = cvtbf(b_.w);                      \
            *(u16x8*)(&Al[P][ch_ * 8]) = o_;                               \
        }                                                                  \
    } while (0)

    // ---- prologue ----
    LOAD_A(0, 0);            // 8
    LOAD_W(0, 0);            // 2
    STAGE_B(0, 0);           // 2   (Bl[0])
    FENCE();
    LOAD_A(1, 1);            // 8   -> 20 outstanding
    FENCE();
    CVT_WRITE_A(0);          // compiler waits vmcnt<=12 for va[0]; writes Al[0]
    FENCE();
    asm volatile("s_waitcnt vmcnt(8) lgkmcnt(0)" ::: "memory");  // W(0),B(0) done
    FENCE();
    __builtin_amdgcn_s_barrier();
    FENCE();
    LOAD_W(1, 1);            // 2
    STAGE_B(1, 1);           // 2   (Bl[1]) -> outstanding: A(1):8, W(1):2, B(1):2
    FENCE();

    // ---- main loop ----
    #pragma unroll
    for (int t = 0; t < NT; ++t) {
        const int cur = t & 1;
        // S1: issue A(t+2) into va[cur] (consumed by CVT last iter)
        if (t + 2 < NT) { LOAD_A(cur, t + 2); }
        FENCE();
        // S2: compute(t)
        #pragma unroll
        for (int kk = 0; kk < 2; ++kk) {
            bf16x8 bfr[2];
            #pragma unroll
            for (int jj = 0; jj < 2; ++jj) {
                int rb = wn * 32 + jj * 16 + l15;
                int jb = (kk * 4 + quad) ^ (rb & 7);
                bfr[jj] = *(const bf16x8*)(&Bl[cur][rb * 64 + jb * 8]);
            }
            bf16x8 wfr = vw[cur][kk];
            #pragma unroll
            for (int i = 0; i < 4; ++i) {
                int rr = wm * 64 + i * 16 + l15;
                int ja = (kk * 4 + quad) ^ (rr & 7);
                bf16x8 af = *(const bf16x8*)(&Al[cur][rr * 64 + ja * 8]);
                #pragma unroll
                for (int jj = 0; jj < 2; ++jj)
                    acc[i][jj] = __builtin_amdgcn_mfma_f32_16x16x32_bf16(
                        af, bfr[jj], acc[i][jj], 0, 0, 0);
                accP[i] = __builtin_amdgcn_mfma_f32_16x16x32_bf16(
                    af, wfr, accP[i], 0, 0, 0);
            }
        }
        FENCE();
        if (t + 1 < NT) {
            // S3: cvt+write A(t+1) -> Al[cur^1] (compiler waits for va[cur^1])
            CVT_WRITE_A(cur ^ 1);
            FENCE();
            // S4: counted drain + raw barrier; A(t+2) stays in flight
            if (t + 2 < NT) {
                asm volatile("s_waitcnt vmcnt(8) lgkmcnt(0)" ::: "memory");
            } else {
                asm volatile("s_waitcnt vmcnt(0) lgkmcnt(0)" ::: "memory");
            }
            FENCE();
            __builtin_amdgcn_s_barrier();
            FENCE();
            // S5: issue W(t+2), B(t+2->Bl[cur]) — all waves past Bl[cur] reads
            if (t + 2 < NT) { LOAD_W(cur, t + 2); STAGE_B(cur, t + 2); }
            FENCE();
        }
    }

    // ---- s partials: this wave owns pairs p = wn*8 + (l15>>1) ----
    {
        const int p = wn * 8 + (l15 >> 1);
        const float bB = b2[p], bC = b3[p];
        #pragma unroll
        for (int i = 0; i < 4; ++i) {
            float sacc[4];
            #pragma unroll
            for (int r = 0; r < 4; ++r) {
                float v = accP[i][r];
                float pv = __shfl_xor(v, 1, 64);
                sacc[r] = (l15 & 1) ? (pv + bB) * (v + bC)
                                    : (v + bB) * (pv + bC);
                sacc[r] += __shfl_xor(sacc[r], 1, 64);
                sacc[r] += __shfl_xor(sacc[r], 2, 64);
                sacc[r] += __shfl_xor(sacc[r], 4, 64);
                sacc[r] += __shfl_xor(sacc[r], 8, 64);
            }
            if (l15 == 0) {
                #pragma unroll
                for (int r = 0; r < 4; ++r)
                    spart[wn][wm * 64 + i * 16 + quad * 4 + r] = 0.5f * sacc[r];
            }
        }
    }
    __syncthreads();

    // ---- epilogue: C/D layout col = lane&15, row = quad*4 + reg ----
    #pragma unroll
    for (int i = 0; i < 4; ++i) {
        const int rl = wm * 64 + i * 16 + quad * 4;   // local row base
        const int rowbase = m0 + rl;
        float sv4[4];
        #pragma unroll
        for (int r = 0; r < 4; ++r)
            sv4[r] = spart[0][rl + r] + spart[1][rl + r];
        #pragma unroll
        for (int jj = 0; jj < 2; ++jj) {
            int gcol = n0 + wn * 32 + jj * 16 + l15;
            float bias = b1[gcol];
            #pragma unroll
            for (int r = 0; r < 4; ++r) {
                int grow = rowbase + r;
                float v = acc[i][jj][r] + bias;
                float sp = softplus_fast(v);
                float xv = x[grow * DM + gcol];
                y[grow * DM + gcol] = xv * sp * sv4[r];
            }
        }
    }
#undef LOAD_A
#undef LOAD_W
#undef STAGE_B
#undef CVT_WRITE_A
}

extern "C" void kernel_launch(void* const* d_in, const int* in_sizes, int n_in,
                              void* d_out, int out_size, void* d_ws, size_t ws_size,
                              hipStream_t stream) {
    const float* x  = (const float*)d_in[0];
    const float* W1 = (const float*)d_in[1];
    const float* b1 = (const float*)d_in[2];
    const float* W2 = (const float*)d_in[3];
    const float* b2 = (const float*)d_in[4];
    const float* W3 = (const float*)d_in[5];
    const float* b3 = (const float*)d_in[6];
    // d_in[7] = A : unused (multiplied by h0 == 0 in the reference)
    float* y = (float*)d_out;

    unsigned short* w1t  = (unsigned short*)d_ws;                     // 1,179,648 B
    unsigned short* w23t = (unsigned short*)((char*)d_ws + 1179648);  //    49,152 B

    prep_kernel<<<608, 256, 0, stream>>>(W1, W2, W3, w1t, w23t);
    gemm_fused_kernel<<<768, 256, 0, stream>>>(x, w1t, w23t, b1, b2, b3, y);
}

// Round 5
// 115.364 us; speedup vs baseline: 1.0474x; 1.0429x over previous
//
#include <hip/hip_runtime.h>
#include <hip/hip_bf16.h>
#include <math.h>

// Problem: B=4, L=2048 (M = 8192 rows), D_MODEL = 768, N_STATE = 16.
// y[row,d] = x[row,d] * softplus((x@W1+b1)[row,d]) * dot(x@W2+b2, x@W3+b3)[row]
// (dA*h0 term is identically zero; A unused.)
// Ledger: ~62 us harness fills per iter (fixed). R10: direct-from-global GEMM
// loses 2x -> LDS+barrier k-loop. R11 (best, 112.1 us): xb precompute +
// single-buffered async16 k-loop, 128x64 tile, 5 blocks/CU. R12-R15: cvt-in-
// gemm + pipeline attempts all regressed — reg-staged A either gets sunk by
// the compiler (R13, pipeline deleted) or pinned-and-spilled (R15, scratch
// catastrophe); dbuf LDS cut occupancy 20->12 waves. R16 (this round): revert
// to R11 structure exactly, tile 128x64 -> 64x64: LDS 29->21 KB, grid
// 768->1536, ~7 blocks/CU (28 waves) — TLP hides the per-step barrier drains.

#define M_ROWS 8192
#define DM 768
#define NS 16

typedef short bf16x8 __attribute__((ext_vector_type(8)));
typedef float f32x4 __attribute__((ext_vector_type(4)));

__device__ __forceinline__ unsigned short f2bf(float f) {
    union { float f; unsigned u; } v; v.f = f;
    unsigned r = v.u + 0x7FFF + ((v.u >> 16) & 1);   // RNE
    return (unsigned short)(r >> 16);
}
__device__ __forceinline__ float bf2f(unsigned short h) {
    union { unsigned u; float f; } v; v.u = ((unsigned)h) << 16; return v.f;
}
__device__ __forceinline__ void async16(const void* g, void* l) {
    __builtin_amdgcn_global_load_lds(
        (const __attribute__((address_space(1))) void*)g,
        (__attribute__((address_space(3))) void*)l,
        16, 0, 0);
}
// branchless stable softplus: max(v,0) + log(1+exp(-|v|)); HW exp/log.
__device__ __forceinline__ float softplus_fast(float v) {
    return fmaxf(v, 0.f) + __logf(1.f + __expf(-fabsf(v)));
}

// ---- kernel 1: prep (pure streaming, block-specialized) -----------------
// bid [0,32):      w23t build (bf16 n-major, pair-interleaved W2/W3 cols).
// bid [32,608):    W1 [k][n] fp32 -> w1t [n][k] bf16 (32x32 LDS tiles).
// bid [608,6752):  streaming convert x -> xb (bf16), float4/thread.
__global__ __launch_bounds__(256) void prep_kernel(
    const float* __restrict__ x,
    const float* __restrict__ W1,
    const float* __restrict__ W2,
    const float* __restrict__ W3,
    unsigned short* __restrict__ xb,
    unsigned short* __restrict__ w1t,
    unsigned short* __restrict__ w23t)
{
    __shared__ float tile[32][33];
    const int bid = blockIdx.x;
    const int tid = threadIdx.x;
    if (bid < 32) {
        const int n = bid, i = n >> 1;
        const float* src = (n & 1) ? W3 : W2;
        #pragma unroll
        for (int e = 0; e < 3; ++e) {
            int k = e * 256 + tid;
            w23t[n * DM + k] = f2bf(src[k * NS + i]);
        }
    } else if (bid < 608) {
        const int b2i = bid - 32;                // 0..575
        const int n0 = (b2i % 24) * 32, k0 = (b2i / 24) * 32;
        const int tx = tid & 31, ty = tid >> 5;  // 32 x 8
        #pragma unroll
        for (int i = 0; i < 4; ++i) {
            int k = ty + i * 8;
            tile[k][tx] = W1[(k0 + k) * DM + n0 + tx];
        }
        __syncthreads();
        #pragma unroll
        for (int i = 0; i < 4; ++i) {
            int n = ty + i * 8;
            w1t[(n0 + n) * DM + k0 + tx] = f2bf(tile[tx][n]);
        }
    } else {
        int i = (bid - 608) * 256 + tid;         // one float4 per thread
        float4 v = ((const float4*)x)[i];
        ushort4 o;
        o.x = f2bf(v.x); o.y = f2bf(v.y); o.z = f2bf(v.z); o.w = f2bf(v.w);
        ((ushort4*)xb)[i] = o;
    }
}

// ---- kernel 2: fused GEMM + integrated s + softplus/scale epilogue ------
// R11-exact k-loop structure (single-buffered LDS, 2 barriers/step, 256 thr,
// 4 waves 2x2, XCD swizzle) at 64x64 tile, BK=64. LDS ~21 KB -> ~7 blocks/CU
// (28 waves): the per-step vmcnt(0)+barrier drain of one block overlaps with
// ~6 other blocks' compute. Wave (wm,wn) owns rows [wm*32,+32), cols
// [wn*32,+32); P-gemm reuses A-frags (accP); pair-product s reduces via the
// verified shfl algebra, cross-wn combine through 0.5 KB LDS.
__global__ __launch_bounds__(256) void gemm_fused_kernel(
    const unsigned short* __restrict__ xb,    // [8192][768] bf16
    const unsigned short* __restrict__ w1t,   // [768][768] bf16, n-major
    const unsigned short* __restrict__ w23t,  // [32][768] bf16, pair-interleaved
    const float* __restrict__ b1,
    const float* __restrict__ b2, const float* __restrict__ b3,
    float* __restrict__ y)
{
    __shared__ unsigned short Al[64 * 64];    //  8 KB
    __shared__ unsigned short Bl[64 * 64];    //  8 KB
    __shared__ unsigned short Wl[32 * 64];    //  4 KB
    __shared__ float spart[2][64];            //  0.5 KB
    const int b = blockIdx.x;
    const int c = b & 7, j = b >> 3;          // j in [0,192)
    const int m0 = (c * 16 + j / 12) * 64;    // 128 m-tiles, XCD-contiguous
    const int n0 = (j % 12) * 64;
    const int tid  = threadIdx.x;
    const int lane = tid & 63;
    const int wave = tid >> 6;
    const int wm = wave >> 1, wn = wave & 1;
    const int l15 = lane & 15, quad = lane >> 4;

    f32x4 acc[2][2];
    f32x4 accP[2];
    #pragma unroll
    for (int i = 0; i < 2; ++i) {
        accP[i] = (f32x4){0.f, 0.f, 0.f, 0.f};
        #pragma unroll
        for (int jj = 0; jj < 2; ++jj)
            acc[i][jj] = (f32x4){0.f, 0.f, 0.f, 0.f};
    }

    for (int k0 = 0; k0 < DM; k0 += 64) {
        #pragma unroll
        for (int i = 0; i < 2; ++i) {         // A: 512 chunks
            int ch = tid + i * 256;
            int r = ch >> 3, jg = (ch & 7) ^ (r & 7);
            async16(xb + (m0 + r) * DM + k0 + jg * 8, Al + ch * 8);
        }
        #pragma unroll
        for (int i = 0; i < 2; ++i) {         // B: 512 chunks
            int ch = tid + i * 256;
            int r = ch >> 3, jg = (ch & 7) ^ (r & 7);
            async16(w1t + (n0 + r) * DM + k0 + jg * 8, Bl + ch * 8);
        }
        {                                      // W23: 256 chunks
            int ch = tid;
            int r = ch >> 3, jg = (ch & 7) ^ (r & 7);
            async16(w23t + r * DM + k0 + jg * 8, Wl + ch * 8);
        }
        __syncthreads();

        #pragma unroll
        for (int kk = 0; kk < 2; ++kk) {
            bf16x8 bfr[2], wfr;
            #pragma unroll
            for (int jj = 0; jj < 2; ++jj) {
                int rb = wn * 32 + jj * 16 + l15;
                int jb = (kk * 4 + quad) ^ (rb & 7);
                bfr[jj] = *(const bf16x8*)(Bl + rb * 64 + jb * 8);
            }
            {
                int rw = wn * 16 + l15;
                int jw = (kk * 4 + quad) ^ (rw & 7);
                wfr = *(const bf16x8*)(Wl + rw * 64 + jw * 8);
            }
            #pragma unroll
            for (int i = 0; i < 2; ++i) {
                int rr = wm * 32 + i * 16 + l15;
                int ja = (kk * 4 + quad) ^ (rr & 7);
                bf16x8 af = *(const bf16x8*)(Al + rr * 64 + ja * 8);
                #pragma unroll
                for (int jj = 0; jj < 2; ++jj)
                    acc[i][jj] = __builtin_amdgcn_mfma_f32_16x16x32_bf16(
                        af, bfr[jj], acc[i][jj], 0, 0, 0);
                accP[i] = __builtin_amdgcn_mfma_f32_16x16x32_bf16(
                    af, wfr, accP[i], 0, 0, 0);
            }
        }
        __syncthreads();
    }

    // ---- s partials: this wave owns pairs p = wn*8 + (l15>>1) ----
    {
        const int p = wn * 8 + (l15 >> 1);
        const float bB = b2[p], bC = b3[p];
        #pragma unroll
        for (int i = 0; i < 2; ++i) {
            float sacc[4];
            #pragma unroll
            for (int r = 0; r < 4; ++r) {
                float v = accP[i][r];
                float pv = __shfl_xor(v, 1, 64);
                sacc[r] = (l15 & 1) ? (pv + bB) * (v + bC)
                                    : (v + bB) * (pv + bC);
                sacc[r] += __shfl_xor(sacc[r], 1, 64);
                sacc[r] += __shfl_xor(sacc[r], 2, 64);
                sacc[r] += __shfl_xor(sacc[r], 4, 64);
                sacc[r] += __shfl_xor(sacc[r], 8, 64);
            }
            if (l15 == 0) {
                #pragma unroll
                for (int r = 0; r < 4; ++r)
                    spart[wn][wm * 32 + i * 16 + quad * 4 + r] = 0.5f * sacc[r];
            }
        }
    }
    __syncthreads();

    // ---- epilogue: C/D layout col = lane&15, row = quad*4 + reg ----
    #pragma unroll
    for (int i = 0; i < 2; ++i) {
        const int rl = wm * 32 + i * 16 + quad * 4;   // local row base
        const int rowbase = m0 + rl;
        float sv4[4];
        #pragma unroll
        for (int r = 0; r < 4; ++r)
            sv4[r] = spart[0][rl + r] + spart[1][rl + r];
        #pragma unroll
        for (int jj = 0; jj < 2; ++jj) {
            int gcol = n0 + wn * 32 + jj * 16 + l15;
            float bias = b1[gcol];
            #pragma unroll
            for (int r = 0; r < 4; ++r) {
                int grow = rowbase + r;
                float v = acc[i][jj][r] + bias;
                float sp = softplus_fast(v);
                float xv = bf2f(xb[grow * DM + gcol]);
                y[grow * DM + gcol] = xv * sp * sv4[r];
            }
        }
    }
}

extern "C" void kernel_launch(void* const* d_in, const int* in_sizes, int n_in,
                              void* d_out, int out_size, void* d_ws, size_t ws_size,
                              hipStream_t stream) {
    const float* x  = (const float*)d_in[0];
    const float* W1 = (const float*)d_in[1];
    const float* b1 = (const float*)d_in[2];
    const float* W2 = (const float*)d_in[3];
    const float* b2 = (const float*)d_in[4];
    const float* W3 = (const float*)d_in[5];
    const float* b3 = (const float*)d_in[6];
    // d_in[7] = A : unused (multiplied by h0 == 0 in the reference)
    float* y = (float*)d_out;

    unsigned short* xb   = (unsigned short*)d_ws;                      // 12,582,912 B
    unsigned short* w1t  = (unsigned short*)((char*)d_ws + 12582912);  //  1,179,648 B
    unsigned short* w23t = (unsigned short*)((char*)d_ws + 13762560);  //     49,152 B

    prep_kernel<<<6752, 256, 0, stream>>>(x, W1, W2, W3, xb, w1t, w23t);
    gemm_fused_kernel<<<1536, 256, 0, stream>>>(xb, w1t, w23t, b1, b2, b3, y);
}